// Round 12
// baseline (1065.796 us; speedup 1.0000x reference)
//
#include <hip/hip_runtime.h>

#define TT 512   // sequence length
#define BB 64    // batch
#define HH 128   // hidden
#define G4 512   // 4*H
#define PF 4     // prefetch ring depth (even, divides TT)

typedef short bf16x8 __attribute__((ext_vector_type(8)));
typedef short s16x4  __attribute__((ext_vector_type(4)));
typedef float f32x4  __attribute__((ext_vector_type(4)));
typedef _Float16 h2f __attribute__((ext_vector_type(2)));
typedef _Float16 h8f __attribute__((ext_vector_type(8)));

__device__ __forceinline__ unsigned short f2bf(float x) {
    unsigned u = __float_as_uint(x);
    u += 0x7fff + ((u >> 16) & 1);           // RNE
    return (unsigned short)(u >> 16);
}
__device__ __forceinline__ float bf2f(unsigned short h) {
    return __uint_as_float(((unsigned)h) << 16);
}
__device__ __forceinline__ float fdot2_(h2f a, h2f b, float c) {
#if __has_builtin(__builtin_amdgcn_fdot2)
    return __builtin_amdgcn_fdot2(a, b, c, false);
#else
    return c + (float)a[0] * (float)b[0] + (float)a[1] * (float)b[1];
#endif
}

// ---------------- fp32 -> bf16 hi/lo split (memory-bound) ----------------
__global__ __launch_bounds__(256) void convert_hilo(
    const float4* __restrict__ src, s16x4* __restrict__ hi,
    s16x4* __restrict__ lo, int n4)
{
    for (int i = blockIdx.x * 256 + threadIdx.x; i < n4; i += gridDim.x * 256) {
        float4 f = src[i];
        float fa[4] = {f.x, f.y, f.z, f.w};
        s16x4 h, l;
        #pragma unroll
        for (int e = 0; e < 4; ++e) {
            unsigned short hh = f2bf(fa[e]);
            h[e] = (short)hh;
            l[e] = (short)f2bf(fa[e] - bf2f(hh));
        }
        hi[i] = h;
        lo[i] = l;
    }
}

// ---------------- MFMA pre-GEMM v2 (proven R6/R7/R11): A pre-split, W in-kernel ----
template<int K>
__global__ __launch_bounds__(256) void gemm_mfma2(
    const short* __restrict__ Ahi, const short* __restrict__ Alo,
    const float* __restrict__ W,
    const float* __restrict__ b0, const float* __restrict__ b1,
    float* __restrict__ C)
{
    constexpr int NC  = K / 32;
    constexpr int LDA = 40;                  // shorts per staged row (32 + 8 pad)
    __shared__ short Ahi_s[128 * LDA], Alo_s[128 * LDA];
    __shared__ short Whi_s[128 * LDA], Wlo_s[128 * LDA];

    const int bm  = blockIdx.x * 128;
    const int bn  = blockIdx.y * 128;
    const int tid = threadIdx.x;
    const int wv  = tid >> 6;
    const int l   = tid & 63;
    const int jl  = l & 15;
    const int rg  = l >> 4;
    const int wr  = wv >> 1;
    const int wc  = wv & 1;

    const int sr = tid >> 1;
    const int sc = (tid & 1) * 16;

    const short* Aph = Ahi + (size_t)(bm + sr) * K + sc;
    const short* Apl = Alo + (size_t)(bm + sr) * K + sc;
    const float* Wp  = W   + (size_t)(bn + sr) * K + sc;

    f32x4 acc[4][4];
    #pragma unroll
    for (int i = 0; i < 4; ++i)
        #pragma unroll
        for (int j = 0; j < 4; ++j)
            acc[i][j] = (f32x4){0.f, 0.f, 0.f, 0.f};

    bf16x8 pah[2], pal[2];
    float4 pw[4];
    pah[0] = *(const bf16x8*)(Aph);
    pah[1] = *(const bf16x8*)(Aph + 8);
    pal[0] = *(const bf16x8*)(Apl);
    pal[1] = *(const bf16x8*)(Apl + 8);
    #pragma unroll
    for (int q = 0; q < 4; ++q) pw[q] = *(const float4*)(Wp + q * 4);

    #pragma unroll 1
    for (int c = 0; c < NC; ++c) {
        __syncthreads();
        {
            int off = sr * LDA + sc;
            *(bf16x8*)&Ahi_s[off]     = pah[0];
            *(bf16x8*)&Ahi_s[off + 8] = pah[1];
            *(bf16x8*)&Alo_s[off]     = pal[0];
            *(bf16x8*)&Alo_s[off + 8] = pal[1];
            #pragma unroll
            for (int q = 0; q < 4; ++q) {
                float fw[4] = {pw[q].x, pw[q].y, pw[q].z, pw[q].w};
                s16x4 h, lo4;
                #pragma unroll
                for (int e = 0; e < 4; ++e) {
                    unsigned short hh = f2bf(fw[e]);
                    h[e]   = (short)hh;
                    lo4[e] = (short)f2bf(fw[e] - bf2f(hh));
                }
                *(s16x4*)&Whi_s[off + q * 4] = h;
                *(s16x4*)&Wlo_s[off + q * 4] = lo4;
            }
        }
        __syncthreads();
        if (c + 1 < NC) {
            pah[0] = *(const bf16x8*)(Aph + (c + 1) * 32);
            pah[1] = *(const bf16x8*)(Aph + (c + 1) * 32 + 8);
            pal[0] = *(const bf16x8*)(Apl + (c + 1) * 32);
            pal[1] = *(const bf16x8*)(Apl + (c + 1) * 32 + 8);
            #pragma unroll
            for (int q = 0; q < 4; ++q)
                pw[q] = *(const float4*)(Wp + (c + 1) * 32 + q * 4);
        }
        bf16x8 ah[4], al[4], wh[4], wl[4];
        #pragma unroll
        for (int t = 0; t < 4; ++t) {
            int ra = (wr * 64 + t * 16 + jl) * LDA + rg * 8;
            ah[t] = *(const bf16x8*)&Ahi_s[ra];
            al[t] = *(const bf16x8*)&Alo_s[ra];
            int rw = (wc * 64 + t * 16 + jl) * LDA + rg * 8;
            wh[t] = *(const bf16x8*)&Whi_s[rw];
            wl[t] = *(const bf16x8*)&Wlo_s[rw];
        }
        #pragma unroll
        for (int tm = 0; tm < 4; ++tm)
            #pragma unroll
            for (int tn = 0; tn < 4; ++tn) {
                acc[tm][tn] = __builtin_amdgcn_mfma_f32_16x16x32_bf16(ah[tm], wh[tn], acc[tm][tn], 0, 0, 0);
                acc[tm][tn] = __builtin_amdgcn_mfma_f32_16x16x32_bf16(ah[tm], wl[tn], acc[tm][tn], 0, 0, 0);
                acc[tm][tn] = __builtin_amdgcn_mfma_f32_16x16x32_bf16(al[tm], wh[tn], acc[tm][tn], 0, 0, 0);
            }
    }

    // epilogue: C layout col=lane&15 (n), row=(lane>>4)*4+r (m)
    #pragma unroll
    for (int tn = 0; tn < 4; ++tn) {
        int n = bn + wc * 64 + tn * 16 + jl;
        float bias = b0[n] + b1[n];
        #pragma unroll
        for (int tm = 0; tm < 4; ++tm) {
            int m = bm + wr * 64 + tm * 16 + rg * 4;
            #pragma unroll
            for (int r = 0; r < 4; ++r)
                C[(size_t)(m + r) * G4 + n] = acc[tm][tn][r] + bias;
        }
    }
}

// ---------------- LSTM scan v9: 2 sequences per block, v4 lane mapping ----------
// 64 blocks, 512 thr (8 waves). Waves 0-3 = seq A, 4-7 = seq B (independent
// (dir,batch) pairs). HW round-robin puts one wave of EACH seq on every SIMD ->
// the other seq's work fills each seq's barrier/LDS latency window.
// Per seq: v4 mapping (R4-proven): wave wq covers cells wq*32..+31; lane half0
// owns rows {i,g}, half1 {f,o}; dot in fp16/fdot2 (v5-proven); exchange sf,so
// via __shfl(l^32) (v4-proven); half0 owns c, writes h+out. 1 barrier/step.
__global__ __launch_bounds__(512, 2) void lstm_scan_v9(
    const float* __restrict__ pre_f, const float* __restrict__ pre_b,
    const float* __restrict__ whh_f, const float* __restrict__ whh_b,
    float* __restrict__ out)
{
    const int tid  = threadIdx.x;
    const int w    = tid >> 6;       // wave 0..7
    const int sq   = w >> 2;         // seq slot in block (0/1)
    const int wq   = w & 3;          // wave-in-seq
    const int l    = tid & 63;
    const int half = l >> 5;
    const int li   = l & 31;
    const int j    = wq * 32 + li;          // cell 0..127
    const int gA   = half * HH + j;         // i-row or f-row
    const int gB   = (2 + half) * HH + j;   // g-row or o-row

    const int S   = blockIdx.x * 2 + sq;    // global seq 0..127
    const int dir = S >> 6;
    const int b   = S & 63;
    const float* __restrict__ pre  = dir ? pre_b : pre_f;
    const float* __restrict__ w_hh = dir ? whh_b : whh_f;

    __shared__ _Float16 h_lds[2][2][HH];    // [seq][dbuf][h]

    // pin both gate rows as packed fp16 (128 dwords; launch_bounds(512,2)
    // gives the 256-VGPR/lane budget)
    h2f wA[64], wB[64];
    #pragma unroll
    for (int k = 0; k < HH; k += 4) {
        float4 fa = *(const float4*)&w_hh[(size_t)gA * HH + k];
        wA[k / 2]     = (h2f){(_Float16)fa.x, (_Float16)fa.y};
        wA[k / 2 + 1] = (h2f){(_Float16)fa.z, (_Float16)fa.w};
        float4 fb = *(const float4*)&w_hh[(size_t)gB * HH + k];
        wB[k / 2]     = (h2f){(_Float16)fb.x, (_Float16)fb.y};
        wB[k / 2 + 1] = (h2f){(_Float16)fb.z, (_Float16)fb.w};
    }

    ((_Float16*)h_lds)[tid] = (_Float16)0.f;   // 512 entries, 512 threads

    const size_t baseA = (size_t)b * TT * G4 + gA;
    const size_t baseB = (size_t)b * TT * G4 + gB;
    float pfA[PF], pfB[PF];
    #pragma unroll
    for (int u = 0; u < PF; ++u) {
        int tau = dir ? (TT - 1 - u) : u;
        pfA[u] = pre[baseA + (size_t)tau * G4];
        pfB[u] = pre[baseB + (size_t)tau * G4];
    }

    float c = 0.f;
    const float ASIG = -1.4426950408889634f;  // -log2(e)
    const float ATAN =  2.8853900817779268f;  // 2*log2(e)
    const float aB   = half ? ASIG : ATAN;    // half0's B-row is tanh(g)

    float* outp = out + (size_t)b * TT * (2 * HH) + dir * HH + j
                + (dir ? (size_t)(TT - 1) * (2 * HH) : (size_t)0);
    const int ostep = dir ? -(2 * HH) : (2 * HH);

    __syncthreads();

    for (int s0 = 0; s0 < TT; s0 += PF) {
        #pragma unroll
        for (int u = 0; u < PF; ++u) {
            const int s = s0 + u;
            const int cur = u & 1;           // PF even -> parity(s) == parity(u)
            const _Float16* hb = h_lds[sq][cur];

            float a0 = 0.f, a1 = 0.f, a2 = 0.f, a3 = 0.f;
            float c0 = 0.f, c1 = 0.f, c2 = 0.f, c3 = 0.f;
            #pragma unroll
            for (int k8 = 0; k8 < 16; ++k8) {
                union { h8f v; h2f p[4]; } hu;
                hu.v = *(const h8f*)&hb[k8 * 8];   // wave-uniform broadcast b128
                a0 = fdot2_(wA[k8 * 4 + 0], hu.p[0], a0);
                a1 = fdot2_(wA[k8 * 4 + 1], hu.p[1], a1);
                a2 = fdot2_(wA[k8 * 4 + 2], hu.p[2], a2);
                a3 = fdot2_(wA[k8 * 4 + 3], hu.p[3], a3);
                c0 = fdot2_(wB[k8 * 4 + 0], hu.p[0], c0);
                c1 = fdot2_(wB[k8 * 4 + 1], hu.p[1], c1);
                c2 = fdot2_(wB[k8 * 4 + 2], hu.p[2], c2);
                c3 = fdot2_(wB[k8 * 4 + 3], hu.p[3], c3);
            }
            float gateA = pfA[u] + ((a0 + a1) + (a2 + a3));
            float gateB = pfB[u] + ((c0 + c1) + (c2 + c3));

            // ring refill AFTER gates read their pf (R8-R10 lesson), clamped
            {
                int sn = s + PF;
                int taun = dir ? (TT - 1 - sn) : sn;
                taun = taun < 0 ? 0 : (taun > TT - 1 ? TT - 1 : taun);
                pfA[u] = pre[baseA + (size_t)taun * G4];
                pfB[u] = pre[baseB + (size_t)taun * G4];
            }

            // own-gate activations (v4-proven)
            float eA = __builtin_amdgcn_exp2f(ASIG * gateA);
            float vA = __builtin_amdgcn_rcpf(1.f + eA);            // si or sf
            float eB = __builtin_amdgcn_exp2f(aB * gateB);
            float rB = __builtin_amdgcn_rcpf(1.f + eB);
            float vB = half ? rB : (1.f - 2.f * rB);               // so or tg

            // pass (sf, so) from half1 to half0 partner (v4-proven)
            float sfx = __shfl(vA, l ^ 32);
            float sox = __shfl(vB, l ^ 32);

            if (half == 0) {
                c = fmaf(sfx, c, vA * vB);                          // f*c + i*g
                float e2 = __builtin_amdgcn_exp2f(ATAN * c);
                float r2 = __builtin_amdgcn_rcpf(1.f + e2);
                float h  = sox * (1.f - 2.f * r2);                  // o * tanh(c)
                h_lds[sq][cur ^ 1][j] = (_Float16)h;
                outp[0] = h;
            }
            outp += ostep;
            __syncthreads();
        }
    }
}

// ---------------- FC v2 (proven R7) ----------------
__global__ __launch_bounds__(256) void fc_v2(
    const float* __restrict__ h2, const float* __restrict__ w_fc,
    const float* __restrict__ b_fc, float* __restrict__ out)
{
    __shared__ float4 wsT[64][64];          // [k4][n]
    const int tid = threadIdx.x;
    const int bm  = blockIdx.x * 64;
    const int n   = tid & 63;
    const int mg  = tid >> 6;

    #pragma unroll
    for (int qq = 0; qq < 16; ++qq) {
        int id = qq * 256 + tid;
        int nn = id >> 6, k4 = id & 63;
        wsT[k4][nn] = *(const float4*)&w_fc[(size_t)nn * 256 + k4 * 4];
    }
    __syncthreads();

    const float bias = b_fc[n];
    const float* hrow = h2 + (size_t)(bm + mg * 16) * 256;

    float acc[16];
    #pragma unroll
    for (int mi = 0; mi < 16; ++mi) acc[mi] = 0.f;

    #pragma unroll 2
    for (int k4 = 0; k4 < 64; ++k4) {
        float4 w4 = wsT[k4][n];
        #pragma unroll
        for (int mi = 0; mi < 16; ++mi) {
            float4 h4 = *(const float4*)(hrow + (size_t)mi * 256 + k4 * 4);
            acc[mi] = fmaf(h4.x, w4.x, acc[mi]);
            acc[mi] = fmaf(h4.y, w4.y, acc[mi]);
            acc[mi] = fmaf(h4.z, w4.z, acc[mi]);
            acc[mi] = fmaf(h4.w, w4.w, acc[mi]);
        }
    }
    #pragma unroll
    for (int mi = 0; mi < 16; ++mi)
        out[(size_t)(bm + mg * 16 + mi) * 64 + n] = acc[mi] + bias;
}

extern "C" void kernel_launch(void* const* d_in, const int* in_sizes, int n_in,
                              void* d_out, int out_size, void* d_ws, size_t ws_size,
                              hipStream_t stream) {
    const float* x        = (const float*)d_in[0];
    const float* w_ih_l0  = (const float*)d_in[1];
    const float* w_hh_l0  = (const float*)d_in[2];
    const float* b_ih_l0  = (const float*)d_in[3];
    const float* b_hh_l0  = (const float*)d_in[4];
    const float* w_ih_l0r = (const float*)d_in[5];
    const float* w_hh_l0r = (const float*)d_in[6];
    const float* b_ih_l0r = (const float*)d_in[7];
    const float* b_hh_l0r = (const float*)d_in[8];
    const float* w_ih_l1  = (const float*)d_in[9];
    const float* w_hh_l1  = (const float*)d_in[10];
    const float* b_ih_l1  = (const float*)d_in[11];
    const float* b_hh_l1  = (const float*)d_in[12];
    const float* w_ih_l1r = (const float*)d_in[13];
    const float* w_hh_l1r = (const float*)d_in[14];
    const float* b_ih_l1r = (const float*)d_in[15];
    const float* b_hh_l1r = (const float*)d_in[16];
    const float* w_fc     = (const float*)d_in[17];
    const float* b_fc     = (const float*)d_in[18];

    float* ws    = (float*)d_ws;
    float* pre_f = ws;                       // 16,777,216 floats
    float* pre_b = ws + 16777216;            // 16,777,216 floats
    float* out0  = ws + 2 * 16777216;        // 8,388,608 floats
    float* out1  = out0 + 8388608;           // 8,388,608 floats

    // A hi/lo aliases (lifetimes proven R6/R7):
    short* xhi  = (short*)out0;
    short* xlo  = xhi + 2097152;
    short* a1hi = (short*)out1;
    short* a1lo = a1hi + 8388608;

    dim3 gg(256, 4);  // M/128 x 512/128

    // Layer 0
    convert_hilo<<<2048, 256, 0, stream>>>((const float4*)x, (s16x4*)xhi, (s16x4*)xlo, 524288);
    gemm_mfma2<64><<<gg, 256, 0, stream>>>(xhi, xlo, w_ih_l0,  b_ih_l0,  b_hh_l0,  pre_f);
    gemm_mfma2<64><<<gg, 256, 0, stream>>>(xhi, xlo, w_ih_l0r, b_ih_l0r, b_hh_l0r, pre_b);
    lstm_scan_v9<<<64, 512, 0, stream>>>(pre_f, pre_b, w_hh_l0, w_hh_l0r, out0);

    // Layer 1
    convert_hilo<<<2048, 256, 0, stream>>>((const float4*)out0, (s16x4*)a1hi, (s16x4*)a1lo, 2097152);
    gemm_mfma2<256><<<gg, 256, 0, stream>>>(a1hi, a1lo, w_ih_l1,  b_ih_l1,  b_hh_l1,  pre_f);
    gemm_mfma2<256><<<gg, 256, 0, stream>>>(a1hi, a1lo, w_ih_l1r, b_ih_l1r, b_hh_l1r, pre_b);
    lstm_scan_v9<<<64, 512, 0, stream>>>(pre_f, pre_b, w_hh_l1, w_hh_l1r, out1);

    // FC
    fc_v2<<<512, 256, 0, stream>>>(out1, w_fc, b_fc, (float*)d_out);
}

// Round 13
// 771.027 us; speedup vs baseline: 1.3823x; 1.3823x over previous
//
#include <hip/hip_runtime.h>

#define TT 512   // sequence length
#define BB 64    // batch
#define HH 128   // hidden
#define G4 512   // 4*H
#define PF 8     // prefetch ring depth (even, divides TT)

typedef short bf16x8 __attribute__((ext_vector_type(8)));
typedef short s16x4  __attribute__((ext_vector_type(4)));
typedef float f32x4  __attribute__((ext_vector_type(4)));
typedef _Float16 h2f __attribute__((ext_vector_type(2)));
typedef _Float16 h8f __attribute__((ext_vector_type(8)));

__device__ __forceinline__ unsigned short f2bf(float x) {
    unsigned u = __float_as_uint(x);
    u += 0x7fff + ((u >> 16) & 1);           // RNE
    return (unsigned short)(u >> 16);
}
__device__ __forceinline__ float bf2f(unsigned short h) {
    return __uint_as_float(((unsigned)h) << 16);
}
__device__ __forceinline__ float fdot2_(h2f a, h2f b, float c) {
#if __has_builtin(__builtin_amdgcn_fdot2)
    return __builtin_amdgcn_fdot2(a, b, c, false);
#else
    return c + (float)a[0] * (float)b[0] + (float)a[1] * (float)b[1];
#endif
}

// ---------------- fp32 -> bf16 hi/lo split (memory-bound) ----------------
__global__ __launch_bounds__(256) void convert_hilo(
    const float4* __restrict__ src, s16x4* __restrict__ hi,
    s16x4* __restrict__ lo, int n4)
{
    for (int i = blockIdx.x * 256 + threadIdx.x; i < n4; i += gridDim.x * 256) {
        float4 f = src[i];
        float fa[4] = {f.x, f.y, f.z, f.w};
        s16x4 h, l;
        #pragma unroll
        for (int e = 0; e < 4; ++e) {
            unsigned short hh = f2bf(fa[e]);
            h[e] = (short)hh;
            l[e] = (short)f2bf(fa[e] - bf2f(hh));
        }
        hi[i] = h;
        lo[i] = l;
    }
}

// ---------------- MFMA pre-GEMM v2 (proven R6/R7/R11): A pre-split, W in-kernel ----
template<int K>
__global__ __launch_bounds__(256) void gemm_mfma2(
    const short* __restrict__ Ahi, const short* __restrict__ Alo,
    const float* __restrict__ W,
    const float* __restrict__ b0, const float* __restrict__ b1,
    float* __restrict__ C)
{
    constexpr int NC  = K / 32;
    constexpr int LDA = 40;                  // shorts per staged row (32 + 8 pad)
    __shared__ short Ahi_s[128 * LDA], Alo_s[128 * LDA];
    __shared__ short Whi_s[128 * LDA], Wlo_s[128 * LDA];

    const int bm  = blockIdx.x * 128;
    const int bn  = blockIdx.y * 128;
    const int tid = threadIdx.x;
    const int wv  = tid >> 6;
    const int l   = tid & 63;
    const int jl  = l & 15;
    const int rg  = l >> 4;
    const int wr  = wv >> 1;
    const int wc  = wv & 1;

    const int sr = tid >> 1;
    const int sc = (tid & 1) * 16;

    const short* Aph = Ahi + (size_t)(bm + sr) * K + sc;
    const short* Apl = Alo + (size_t)(bm + sr) * K + sc;
    const float* Wp  = W   + (size_t)(bn + sr) * K + sc;

    f32x4 acc[4][4];
    #pragma unroll
    for (int i = 0; i < 4; ++i)
        #pragma unroll
        for (int j = 0; j < 4; ++j)
            acc[i][j] = (f32x4){0.f, 0.f, 0.f, 0.f};

    bf16x8 pah[2], pal[2];
    float4 pw[4];
    pah[0] = *(const bf16x8*)(Aph);
    pah[1] = *(const bf16x8*)(Aph + 8);
    pal[0] = *(const bf16x8*)(Apl);
    pal[1] = *(const bf16x8*)(Apl + 8);
    #pragma unroll
    for (int q = 0; q < 4; ++q) pw[q] = *(const float4*)(Wp + q * 4);

    #pragma unroll 1
    for (int c = 0; c < NC; ++c) {
        __syncthreads();
        {
            int off = sr * LDA + sc;
            *(bf16x8*)&Ahi_s[off]     = pah[0];
            *(bf16x8*)&Ahi_s[off + 8] = pah[1];
            *(bf16x8*)&Alo_s[off]     = pal[0];
            *(bf16x8*)&Alo_s[off + 8] = pal[1];
            #pragma unroll
            for (int q = 0; q < 4; ++q) {
                float fw[4] = {pw[q].x, pw[q].y, pw[q].z, pw[q].w};
                s16x4 h, lo4;
                #pragma unroll
                for (int e = 0; e < 4; ++e) {
                    unsigned short hh = f2bf(fw[e]);
                    h[e]   = (short)hh;
                    lo4[e] = (short)f2bf(fw[e] - bf2f(hh));
                }
                *(s16x4*)&Whi_s[off + q * 4] = h;
                *(s16x4*)&Wlo_s[off + q * 4] = lo4;
            }
        }
        __syncthreads();
        if (c + 1 < NC) {
            pah[0] = *(const bf16x8*)(Aph + (c + 1) * 32);
            pah[1] = *(const bf16x8*)(Aph + (c + 1) * 32 + 8);
            pal[0] = *(const bf16x8*)(Apl + (c + 1) * 32);
            pal[1] = *(const bf16x8*)(Apl + (c + 1) * 32 + 8);
            #pragma unroll
            for (int q = 0; q < 4; ++q)
                pw[q] = *(const float4*)(Wp + (c + 1) * 32 + q * 4);
        }
        bf16x8 ah[4], al[4], wh[4], wl[4];
        #pragma unroll
        for (int t = 0; t < 4; ++t) {
            int ra = (wr * 64 + t * 16 + jl) * LDA + rg * 8;
            ah[t] = *(const bf16x8*)&Ahi_s[ra];
            al[t] = *(const bf16x8*)&Alo_s[ra];
            int rw = (wc * 64 + t * 16 + jl) * LDA + rg * 8;
            wh[t] = *(const bf16x8*)&Whi_s[rw];
            wl[t] = *(const bf16x8*)&Wlo_s[rw];
        }
        #pragma unroll
        for (int tm = 0; tm < 4; ++tm)
            #pragma unroll
            for (int tn = 0; tn < 4; ++tn) {
                acc[tm][tn] = __builtin_amdgcn_mfma_f32_16x16x32_bf16(ah[tm], wh[tn], acc[tm][tn], 0, 0, 0);
                acc[tm][tn] = __builtin_amdgcn_mfma_f32_16x16x32_bf16(ah[tm], wl[tn], acc[tm][tn], 0, 0, 0);
                acc[tm][tn] = __builtin_amdgcn_mfma_f32_16x16x32_bf16(al[tm], wh[tn], acc[tm][tn], 0, 0, 0);
            }
    }

    // epilogue: C layout col=lane&15 (n), row=(lane>>4)*4+r (m)
    #pragma unroll
    for (int tn = 0; tn < 4; ++tn) {
        int n = bn + wc * 64 + tn * 16 + jl;
        float bias = b0[n] + b1[n];
        #pragma unroll
        for (int tm = 0; tm < 4; ++tm) {
            int m = bm + wr * 64 + tm * 16 + rg * 4;
            #pragma unroll
            for (int r = 0; r < 4; ++r)
                C[(size_t)(m + r) * G4 + n] = acc[tm][tn][r] + bias;
        }
    }
}

// ---------------- LSTM scan v10: 8 waves, k-split + DPP row-shift:8 exchange ----
// 128 blocks = 2dir x 64batch, 512 thr (8 waves, 2 waves/SIMD -- v6's proven
// shape). Lane l: q = l&3 (gate), s2 = (l>>2)&1, kh = (l>>3)&1 (k-half),
// g2 = l>>4. Cells jA = w*16 + g2*4 + s2*2, jB = jA+1. Lane dots gate rows
// (q,jA),(q,jB) over k in [kh*64, kh*64+64) -> 8 b128 h-reads (HALF of v6's 16;
// LDS ops/CU/step 136->72, the measured v6 wall). Partner = l^8, within the
// 16-lane DPP row: exchange via row_shl:8 / row_shr:8 (pure VALU, ~6 cyc --
// not v7's 100-cyc ds_swizzle). Direction convention proven by R9/R10
// bit-equivalence + R11 pass. kh0 finishes cell jA, kh1 finishes jB.
// Quad-perm gate gather + q==0 tail identical to v6. pf read BEFORE refill.
__global__ __launch_bounds__(512) void lstm_scan_v10(
    const float* __restrict__ pre_f, const float* __restrict__ pre_b,
    const float* __restrict__ whh_f, const float* __restrict__ whh_b,
    float* __restrict__ out)
{
    const int dir = blockIdx.x >> 6;
    const int b   = blockIdx.x & 63;
    const float* __restrict__ pre  = dir ? pre_b : pre_f;
    const float* __restrict__ w_hh = dir ? whh_b : whh_f;

    const int tid = threadIdx.x;
    const int w   = tid >> 6;        // wave 0..7
    const int l   = tid & 63;
    const int q   = l & 3;           // gate type (i,f,g,o)
    const int s2  = (l >> 2) & 1;
    const int kh  = (l >> 3) & 1;    // k-half
    const int g2  = l >> 4;          // 0..3
    const int jA  = w * 16 + g2 * 4 + s2 * 2;  // even cell
    const int jB  = jA + 1;                    // odd cell
    const int jF  = kh ? jB : jA;    // cell this lane finishes
    const int rA  = q * HH + jA;
    const int rB  = q * HH + jB;
    const int rF  = q * HH + jF;

    __shared__ _Float16 h_lds[2][HH];

    // weights: rows rA,rB over this lane's k-half, packed fp16 (64 dwords)
    h2f wA[32], wB[32];
    #pragma unroll
    for (int k = 0; k < 64; k += 4) {
        float4 fa = *(const float4*)&w_hh[(size_t)rA * HH + kh * 64 + k];
        wA[k / 2]     = (h2f){(_Float16)fa.x, (_Float16)fa.y};
        wA[k / 2 + 1] = (h2f){(_Float16)fa.z, (_Float16)fa.w};
        float4 fb = *(const float4*)&w_hh[(size_t)rB * HH + kh * 64 + k];
        wB[k / 2]     = (h2f){(_Float16)fb.x, (_Float16)fb.y};
        wB[k / 2 + 1] = (h2f){(_Float16)fb.z, (_Float16)fb.w};
    }

    if (tid < 2 * HH) ((_Float16*)h_lds)[tid] = (_Float16)0.f;

    const size_t base = (size_t)b * TT * G4 + rF;
    float pf[PF];
    #pragma unroll
    for (int u = 0; u < PF; ++u) {
        int tau = dir ? (TT - 1 - u) : u;
        pf[u] = pre[base + (size_t)tau * G4];
    }

    float c = 0.f;
    const float ASIG = -1.4426950408889634f;  // -log2(e)
    const float ATAN =  2.8853900817779268f;  // 2*log2(e)
    const float aa = (q == 2) ? ATAN : ASIG;

    __syncthreads();

    for (int s0 = 0; s0 < TT; s0 += PF) {
        #pragma unroll
        for (int u = 0; u < PF; ++u) {
            const int s = s0 + u;
            const int cur = u & 1;            // parity(s) == parity(u)

            // partial dots for rows A,B over own k-half (8 broadcast b128 reads)
            const _Float16* hb = &h_lds[cur][kh * 64];
            float a0 = 0.f, a1 = 0.f, a2 = 0.f, a3 = 0.f;
            float c0 = 0.f, c1 = 0.f, c2 = 0.f, c3 = 0.f;
            #pragma unroll
            for (int k8 = 0; k8 < 8; ++k8) {
                union { h8f v; h2f p[4]; } hu;
                hu.v = *(const h8f*)&hb[k8 * 8];
                a0 = fdot2_(wA[k8 * 4 + 0], hu.p[0], a0);
                a1 = fdot2_(wA[k8 * 4 + 1], hu.p[1], a1);
                a2 = fdot2_(wA[k8 * 4 + 2], hu.p[2], a2);
                a3 = fdot2_(wA[k8 * 4 + 3], hu.p[3], a3);
                c0 = fdot2_(wB[k8 * 4 + 0], hu.p[0], c0);
                c1 = fdot2_(wB[k8 * 4 + 1], hu.p[1], c1);
                c2 = fdot2_(wB[k8 * 4 + 2], hu.p[2], c2);
                c3 = fdot2_(wB[k8 * 4 + 3], hu.p[3], c3);
            }
            float pA = (a0 + a1) + (a2 + a3);
            float pB = (c0 + c1) + (c2 + c3);

            // exchange crosswise partial with lane^8, pure VALU DPP (in-row).
            // kh0 keeps A / sends B; kh1 keeps B / sends A (v7-proven pairing).
            // row_shl:8 -> out[i]=in[i+8]; row_shr:8 -> out[i]=in[i-8].
            float own  = kh ? pB : pA;
            float send = kh ? pA : pB;
            int Si = __float_as_int(send);
            float pshl8 = __int_as_float(__builtin_amdgcn_update_dpp(Si, Si, 0x108, 0xF, 0xF, false));
            float pshr8 = __int_as_float(__builtin_amdgcn_update_dpp(Si, Si, 0x118, 0xF, 0xF, false));
            float recv = kh ? pshr8 : pshl8;

            // read THIS step's pre BEFORE the refill clobbers pf[u] (R8-R10 bug)
            float pv = pf[u];

            // ring refill (clamped, branch-free)
            {
                int sn = s + PF;
                int taun = dir ? (TT - 1 - sn) : sn;
                taun = taun < 0 ? 0 : (taun > TT - 1 ? TT - 1 : taun);
                pf[u] = pre[base + (size_t)taun * G4];
            }

            float gate = pv + own + recv;

            // own-gate activation: sigmoid (i,f,o) / tanh (g)
            float e = __builtin_amdgcn_exp2f(aa * gate);
            float r = __builtin_amdgcn_rcpf(1.f + e);
            float v = (q == 2) ? (1.f - 2.f * r) : r;

            // quad rotations (proven v6): at q==0 lanes, sf=f-sig, tg=g-tanh, so=o-sig
            int vi = __float_as_int(v);
            float sf = __int_as_float(__builtin_amdgcn_update_dpp(vi, vi, 0x39, 0xF, 0xF, false));
            float tg = __int_as_float(__builtin_amdgcn_update_dpp(vi, vi, 0x4E, 0xF, 0xF, false));
            float so = __int_as_float(__builtin_amdgcn_update_dpp(vi, vi, 0x93, 0xF, 0xF, false));

            if (q == 0) {
                c = fmaf(sf, c, v * tg);
                float e2 = __builtin_amdgcn_exp2f(ATAN * c);
                float r2 = __builtin_amdgcn_rcpf(1.f + e2);
                float h  = so * (1.f - 2.f * r2);
                h_lds[cur ^ 1][jF] = (_Float16)h;
                int tau = dir ? (TT - 1 - s) : s;
                out[((size_t)b * TT + tau) * (2 * HH) + dir * HH + jF] = h;
            }
            __syncthreads();
        }
    }
}

// ---------------- FC v2 (proven R7) ----------------
__global__ __launch_bounds__(256) void fc_v2(
    const float* __restrict__ h2, const float* __restrict__ w_fc,
    const float* __restrict__ b_fc, float* __restrict__ out)
{
    __shared__ float4 wsT[64][64];          // [k4][n]
    const int tid = threadIdx.x;
    const int bm  = blockIdx.x * 64;
    const int n   = tid & 63;
    const int mg  = tid >> 6;

    #pragma unroll
    for (int qq = 0; qq < 16; ++qq) {
        int id = qq * 256 + tid;
        int nn = id >> 6, k4 = id & 63;
        wsT[k4][nn] = *(const float4*)&w_fc[(size_t)nn * 256 + k4 * 4];
    }
    __syncthreads();

    const float bias = b_fc[n];
    const float* hrow = h2 + (size_t)(bm + mg * 16) * 256;

    float acc[16];
    #pragma unroll
    for (int mi = 0; mi < 16; ++mi) acc[mi] = 0.f;

    #pragma unroll 2
    for (int k4 = 0; k4 < 64; ++k4) {
        float4 w4 = wsT[k4][n];
        #pragma unroll
        for (int mi = 0; mi < 16; ++mi) {
            float4 h4 = *(const float4*)(hrow + (size_t)mi * 256 + k4 * 4);
            acc[mi] = fmaf(h4.x, w4.x, acc[mi]);
            acc[mi] = fmaf(h4.y, w4.y, acc[mi]);
            acc[mi] = fmaf(h4.z, w4.z, acc[mi]);
            acc[mi] = fmaf(h4.w, w4.w, acc[mi]);
        }
    }
    #pragma unroll
    for (int mi = 0; mi < 16; ++mi)
        out[(size_t)(bm + mg * 16 + mi) * 64 + n] = acc[mi] + bias;
}

extern "C" void kernel_launch(void* const* d_in, const int* in_sizes, int n_in,
                              void* d_out, int out_size, void* d_ws, size_t ws_size,
                              hipStream_t stream) {
    const float* x        = (const float*)d_in[0];
    const float* w_ih_l0  = (const float*)d_in[1];
    const float* w_hh_l0  = (const float*)d_in[2];
    const float* b_ih_l0  = (const float*)d_in[3];
    const float* b_hh_l0  = (const float*)d_in[4];
    const float* w_ih_l0r = (const float*)d_in[5];
    const float* w_hh_l0r = (const float*)d_in[6];
    const float* b_ih_l0r = (const float*)d_in[7];
    const float* b_hh_l0r = (const float*)d_in[8];
    const float* w_ih_l1  = (const float*)d_in[9];
    const float* w_hh_l1  = (const float*)d_in[10];
    const float* b_ih_l1  = (const float*)d_in[11];
    const float* b_hh_l1  = (const float*)d_in[12];
    const float* w_ih_l1r = (const float*)d_in[13];
    const float* w_hh_l1r = (const float*)d_in[14];
    const float* b_ih_l1r = (const float*)d_in[15];
    const float* b_hh_l1r = (const float*)d_in[16];
    const float* w_fc     = (const float*)d_in[17];
    const float* b_fc     = (const float*)d_in[18];

    float* ws    = (float*)d_ws;
    float* pre_f = ws;                       // 16,777,216 floats
    float* pre_b = ws + 16777216;            // 16,777,216 floats
    float* out0  = ws + 2 * 16777216;        // 8,388,608 floats
    float* out1  = out0 + 8388608;           // 8,388,608 floats

    // A hi/lo aliases (lifetimes proven R6/R7):
    short* xhi  = (short*)out0;
    short* xlo  = xhi + 2097152;
    short* a1hi = (short*)out1;
    short* a1lo = a1hi + 8388608;

    dim3 gg(256, 4);  // M/128 x 512/128

    // Layer 0
    convert_hilo<<<2048, 256, 0, stream>>>((const float4*)x, (s16x4*)xhi, (s16x4*)xlo, 524288);
    gemm_mfma2<64><<<gg, 256, 0, stream>>>(xhi, xlo, w_ih_l0,  b_ih_l0,  b_hh_l0,  pre_f);
    gemm_mfma2<64><<<gg, 256, 0, stream>>>(xhi, xlo, w_ih_l0r, b_ih_l0r, b_hh_l0r, pre_b);
    lstm_scan_v10<<<128, 512, 0, stream>>>(pre_f, pre_b, w_hh_l0, w_hh_l0r, out0);

    // Layer 1
    convert_hilo<<<2048, 256, 0, stream>>>((const float4*)out0, (s16x4*)a1hi, (s16x4*)a1lo, 2097152);
    gemm_mfma2<256><<<gg, 256, 0, stream>>>(a1hi, a1lo, w_ih_l1,  b_ih_l1,  b_hh_l1,  pre_f);
    gemm_mfma2<256><<<gg, 256, 0, stream>>>(a1hi, a1lo, w_ih_l1r, b_ih_l1r, b_hh_l1r, pre_b);
    lstm_scan_v10<<<128, 512, 0, stream>>>(pre_f, pre_b, w_hh_l1, w_hh_l1r, out1);

    // FC
    fc_v2<<<512, 256, 0, stream>>>(out1, w_fc, b_fc, (float*)d_out);
}

// Round 14
// 752.017 us; speedup vs baseline: 1.4173x; 1.0253x over previous
//
#include <hip/hip_runtime.h>

#define TT 512   // sequence length
#define BB 64    // batch
#define HH 128   // hidden
#define G4 512   // 4*H
#define PF 8     // prefetch ring depth == out-chunk size (divides TT)

typedef short bf16x8 __attribute__((ext_vector_type(8)));
typedef short s16x4  __attribute__((ext_vector_type(4)));
typedef float f32x4  __attribute__((ext_vector_type(4)));
typedef _Float16 h2f __attribute__((ext_vector_type(2)));
typedef _Float16 h8f __attribute__((ext_vector_type(8)));

__device__ __forceinline__ unsigned short f2bf(float x) {
    unsigned u = __float_as_uint(x);
    u += 0x7fff + ((u >> 16) & 1);           // RNE
    return (unsigned short)(u >> 16);
}
__device__ __forceinline__ float bf2f(unsigned short h) {
    return __uint_as_float(((unsigned)h) << 16);
}
__device__ __forceinline__ float fdot2_(h2f a, h2f b, float c) {
#if __has_builtin(__builtin_amdgcn_fdot2)
    return __builtin_amdgcn_fdot2(a, b, c, false);
#else
    return c + (float)a[0] * (float)b[0] + (float)a[1] * (float)b[1];
#endif
}

// ---------------- fp32 -> bf16 hi/lo split (memory-bound) ----------------
__global__ __launch_bounds__(256) void convert_hilo(
    const float4* __restrict__ src, s16x4* __restrict__ hi,
    s16x4* __restrict__ lo, int n4)
{
    for (int i = blockIdx.x * 256 + threadIdx.x; i < n4; i += gridDim.x * 256) {
        float4 f = src[i];
        float fa[4] = {f.x, f.y, f.z, f.w};
        s16x4 h, l;
        #pragma unroll
        for (int e = 0; e < 4; ++e) {
            unsigned short hh = f2bf(fa[e]);
            h[e] = (short)hh;
            l[e] = (short)f2bf(fa[e] - bf2f(hh));
        }
        hi[i] = h;
        lo[i] = l;
    }
}

// ---------------- MFMA pre-GEMM v2 (proven R6/R7/R11): A pre-split, W in-kernel ----
template<int K>
__global__ __launch_bounds__(256) void gemm_mfma2(
    const short* __restrict__ Ahi, const short* __restrict__ Alo,
    const float* __restrict__ W,
    const float* __restrict__ b0, const float* __restrict__ b1,
    float* __restrict__ C)
{
    constexpr int NC  = K / 32;
    constexpr int LDA = 40;                  // shorts per staged row (32 + 8 pad)
    __shared__ short Ahi_s[128 * LDA], Alo_s[128 * LDA];
    __shared__ short Whi_s[128 * LDA], Wlo_s[128 * LDA];

    const int bm  = blockIdx.x * 128;
    const int bn  = blockIdx.y * 128;
    const int tid = threadIdx.x;
    const int wv  = tid >> 6;
    const int l   = tid & 63;
    const int jl  = l & 15;
    const int rg  = l >> 4;
    const int wr  = wv >> 1;
    const int wc  = wv & 1;

    const int sr = tid >> 1;
    const int sc = (tid & 1) * 16;

    const short* Aph = Ahi + (size_t)(bm + sr) * K + sc;
    const short* Apl = Alo + (size_t)(bm + sr) * K + sc;
    const float* Wp  = W   + (size_t)(bn + sr) * K + sc;

    f32x4 acc[4][4];
    #pragma unroll
    for (int i = 0; i < 4; ++i)
        #pragma unroll
        for (int j = 0; j < 4; ++j)
            acc[i][j] = (f32x4){0.f, 0.f, 0.f, 0.f};

    bf16x8 pah[2], pal[2];
    float4 pw[4];
    pah[0] = *(const bf16x8*)(Aph);
    pah[1] = *(const bf16x8*)(Aph + 8);
    pal[0] = *(const bf16x8*)(Apl);
    pal[1] = *(const bf16x8*)(Apl + 8);
    #pragma unroll
    for (int q = 0; q < 4; ++q) pw[q] = *(const float4*)(Wp + q * 4);

    #pragma unroll 1
    for (int c = 0; c < NC; ++c) {
        __syncthreads();
        {
            int off = sr * LDA + sc;
            *(bf16x8*)&Ahi_s[off]     = pah[0];
            *(bf16x8*)&Ahi_s[off + 8] = pah[1];
            *(bf16x8*)&Alo_s[off]     = pal[0];
            *(bf16x8*)&Alo_s[off + 8] = pal[1];
            #pragma unroll
            for (int q = 0; q < 4; ++q) {
                float fw[4] = {pw[q].x, pw[q].y, pw[q].z, pw[q].w};
                s16x4 h, lo4;
                #pragma unroll
                for (int e = 0; e < 4; ++e) {
                    unsigned short hh = f2bf(fw[e]);
                    h[e]   = (short)hh;
                    lo4[e] = (short)f2bf(fw[e] - bf2f(hh));
                }
                *(s16x4*)&Whi_s[off + q * 4] = h;
                *(s16x4*)&Wlo_s[off + q * 4] = lo4;
            }
        }
        __syncthreads();
        if (c + 1 < NC) {
            pah[0] = *(const bf16x8*)(Aph + (c + 1) * 32);
            pah[1] = *(const bf16x8*)(Aph + (c + 1) * 32 + 8);
            pal[0] = *(const bf16x8*)(Apl + (c + 1) * 32);
            pal[1] = *(const bf16x8*)(Apl + (c + 1) * 32 + 8);
            #pragma unroll
            for (int q = 0; q < 4; ++q)
                pw[q] = *(const float4*)(Wp + (c + 1) * 32 + q * 4);
        }
        bf16x8 ah[4], al[4], wh[4], wl[4];
        #pragma unroll
        for (int t = 0; t < 4; ++t) {
            int ra = (wr * 64 + t * 16 + jl) * LDA + rg * 8;
            ah[t] = *(const bf16x8*)&Ahi_s[ra];
            al[t] = *(const bf16x8*)&Alo_s[ra];
            int rw = (wc * 64 + t * 16 + jl) * LDA + rg * 8;
            wh[t] = *(const bf16x8*)&Whi_s[rw];
            wl[t] = *(const bf16x8*)&Wlo_s[rw];
        }
        #pragma unroll
        for (int tm = 0; tm < 4; ++tm)
            #pragma unroll
            for (int tn = 0; tn < 4; ++tn) {
                acc[tm][tn] = __builtin_amdgcn_mfma_f32_16x16x32_bf16(ah[tm], wh[tn], acc[tm][tn], 0, 0, 0);
                acc[tm][tn] = __builtin_amdgcn_mfma_f32_16x16x32_bf16(ah[tm], wl[tn], acc[tm][tn], 0, 0, 0);
                acc[tm][tn] = __builtin_amdgcn_mfma_f32_16x16x32_bf16(al[tm], wh[tn], acc[tm][tn], 0, 0, 0);
            }
    }

    // epilogue: C layout col=lane&15 (n), row=(lane>>4)*4+r (m)
    #pragma unroll
    for (int tn = 0; tn < 4; ++tn) {
        int n = bn + wc * 64 + tn * 16 + jl;
        float bias = b0[n] + b1[n];
        #pragma unroll
        for (int tm = 0; tm < 4; ++tm) {
            int m = bm + wr * 64 + tm * 16 + rg * 4;
            #pragma unroll
            for (int r = 0; r < 4; ++r)
                C[(size_t)(m + r) * G4 + n] = acc[tm][tn][r] + bias;
        }
    }
}

// ---------------- LSTM scan v11: v10 compute + memory-timing restructure ----------
// 128 blocks, 512 thr (8 waves). v10's k-split lane map + DPP exchanges (R13-
// proven). NEW vs v10 (both numerically identity-preserving):
//  (1) pre-refill issued at TOP of step (pv captured first): the end-of-step
//      __syncthreads() emits s_waitcnt vmcnt(0) which drains ALL global ops --
//      issuing early gives the cold-HBM gather (~900 cyc) a full-step window.
//  (2) out stores batched: tail writes h (fp32) to LDS ring [2][PF][HH];
//      once per chunk, right after a barrier, all 512 threads burst-write the
//      8 rows coalesced (2 contiguous b32 each) with a full step to drain --
//      removes the per-step scattered-store drain from the barrier.
__global__ __launch_bounds__(512) void lstm_scan_v11(
    const float* __restrict__ pre_f, const float* __restrict__ pre_b,
    const float* __restrict__ whh_f, const float* __restrict__ whh_b,
    float* __restrict__ out)
{
    const int dir = blockIdx.x >> 6;
    const int b   = blockIdx.x & 63;
    const float* __restrict__ pre  = dir ? pre_b : pre_f;
    const float* __restrict__ w_hh = dir ? whh_b : whh_f;

    const int tid = threadIdx.x;
    const int w   = tid >> 6;        // wave 0..7
    const int l   = tid & 63;
    const int q   = l & 3;           // gate type (i,f,g,o)
    const int s2  = (l >> 2) & 1;
    const int kh  = (l >> 3) & 1;    // k-half
    const int g2  = l >> 4;          // 0..3
    const int jA  = w * 16 + g2 * 4 + s2 * 2;  // even cell
    const int jB  = jA + 1;                    // odd cell
    const int jF  = kh ? jB : jA;    // cell this lane finishes
    const int rA  = q * HH + jA;
    const int rB  = q * HH + jB;
    const int rF  = q * HH + jF;

    __shared__ _Float16 h_lds[2][HH];
    __shared__ float oring[2][PF][HH];   // double-buffered output ring (8 KB)

    // weights: rows rA,rB over this lane's k-half, packed fp16 (64 dwords)
    h2f wA[32], wB[32];
    #pragma unroll
    for (int k = 0; k < 64; k += 4) {
        float4 fa = *(const float4*)&w_hh[(size_t)rA * HH + kh * 64 + k];
        wA[k / 2]     = (h2f){(_Float16)fa.x, (_Float16)fa.y};
        wA[k / 2 + 1] = (h2f){(_Float16)fa.z, (_Float16)fa.w};
        float4 fb = *(const float4*)&w_hh[(size_t)rB * HH + kh * 64 + k];
        wB[k / 2]     = (h2f){(_Float16)fb.x, (_Float16)fb.y};
        wB[k / 2 + 1] = (h2f){(_Float16)fb.z, (_Float16)fb.w};
    }

    if (tid < 2 * HH) ((_Float16*)h_lds)[tid] = (_Float16)0.f;

    const size_t base = (size_t)b * TT * G4 + rF;
    float pf[PF];
    #pragma unroll
    for (int u = 0; u < PF; ++u) {
        int tau = dir ? (TT - 1 - u) : u;
        pf[u] = pre[base + (size_t)tau * G4];
    }

    float c = 0.f;
    const float ASIG = -1.4426950408889634f;  // -log2(e)
    const float ATAN =  2.8853900817779268f;  // 2*log2(e)
    const float aa = (q == 2) ? ATAN : ASIG;

    // burst-write constants (thread t covers step s0+(t>>6), cols t&63, +64)
    const int s_loc = tid >> 6;
    const int c64   = tid & 63;

    __syncthreads();

    for (int s0 = 0; s0 < TT; s0 += PF) {
        const int p = (s0 >> 3) & 1;          // ring parity for this chunk
        #pragma unroll
        for (int u = 0; u < PF; ++u) {
            const int s = s0 + u;
            const int cur = u & 1;            // parity(s) == parity(u)

            // (1) capture this step's pre, then ISSUE refill immediately --
            // maximizes the load->barrier window (drained at end-of-step)
            float pv = pf[u];
            {
                int sn = s + PF;
                int taun = dir ? (TT - 1 - sn) : sn;
                taun = taun < 0 ? 0 : (taun > TT - 1 ? TT - 1 : taun);
                pf[u] = pre[base + (size_t)taun * G4];
            }

            // partial dots for rows A,B over own k-half (8 broadcast b128 reads)
            const _Float16* hb = &h_lds[cur][kh * 64];
            float a0 = 0.f, a1 = 0.f, a2 = 0.f, a3 = 0.f;
            float c0 = 0.f, c1 = 0.f, c2 = 0.f, c3 = 0.f;
            #pragma unroll
            for (int k8 = 0; k8 < 8; ++k8) {
                union { h8f v; h2f p_[4]; } hu;
                hu.v = *(const h8f*)&hb[k8 * 8];
                a0 = fdot2_(wA[k8 * 4 + 0], hu.p_[0], a0);
                a1 = fdot2_(wA[k8 * 4 + 1], hu.p_[1], a1);
                a2 = fdot2_(wA[k8 * 4 + 2], hu.p_[2], a2);
                a3 = fdot2_(wA[k8 * 4 + 3], hu.p_[3], a3);
                c0 = fdot2_(wB[k8 * 4 + 0], hu.p_[0], c0);
                c1 = fdot2_(wB[k8 * 4 + 1], hu.p_[1], c1);
                c2 = fdot2_(wB[k8 * 4 + 2], hu.p_[2], c2);
                c3 = fdot2_(wB[k8 * 4 + 3], hu.p_[3], c3);
            }
            float pA = (a0 + a1) + (a2 + a3);
            float pB = (c0 + c1) + (c2 + c3);

            // crosswise partial with lane^8, pure VALU DPP (R13-proven).
            float own  = kh ? pB : pA;
            float send = kh ? pA : pB;
            int Si = __float_as_int(send);
            float pshl8 = __int_as_float(__builtin_amdgcn_update_dpp(Si, Si, 0x108, 0xF, 0xF, false));
            float pshr8 = __int_as_float(__builtin_amdgcn_update_dpp(Si, Si, 0x118, 0xF, 0xF, false));
            float recv = kh ? pshr8 : pshl8;

            float gate = pv + own + recv;

            // own-gate activation: sigmoid (i,f,o) / tanh (g)
            float e = __builtin_amdgcn_exp2f(aa * gate);
            float r = __builtin_amdgcn_rcpf(1.f + e);
            float v = (q == 2) ? (1.f - 2.f * r) : r;

            // quad rotations (proven v6): at q==0 lanes, sf=f-sig, tg=g-tanh, so=o-sig
            int vi = __float_as_int(v);
            float sf = __int_as_float(__builtin_amdgcn_update_dpp(vi, vi, 0x39, 0xF, 0xF, false));
            float tg = __int_as_float(__builtin_amdgcn_update_dpp(vi, vi, 0x4E, 0xF, 0xF, false));
            float so = __int_as_float(__builtin_amdgcn_update_dpp(vi, vi, 0x93, 0xF, 0xF, false));

            if (q == 0) {
                c = fmaf(sf, c, v * tg);
                float e2 = __builtin_amdgcn_exp2f(ATAN * c);
                float r2 = __builtin_amdgcn_rcpf(1.f + e2);
                float h  = so * (1.f - 2.f * r2);
                h_lds[cur ^ 1][jF] = (_Float16)h;
                oring[p][u][jF] = h;             // (2) stage output in LDS ring
            }
            __syncthreads();
        }

        // (2) coalesced burst-write of the chunk just finished (after its last
        // barrier; next chunk writes the opposite ring parity -> no race).
        {
            int sb = s0 + s_loc;
            int tau = dir ? (TT - 1 - sb) : sb;
            float* orow = out + ((size_t)b * TT + tau) * (2 * HH) + dir * HH;
            orow[c64]      = oring[p][s_loc][c64];
            orow[c64 + 64] = oring[p][s_loc][c64 + 64];
        }
    }
}

// ---------------- FC v2 (proven R7) ----------------
__global__ __launch_bounds__(256) void fc_v2(
    const float* __restrict__ h2, const float* __restrict__ w_fc,
    const float* __restrict__ b_fc, float* __restrict__ out)
{
    __shared__ float4 wsT[64][64];          // [k4][n]
    const int tid = threadIdx.x;
    const int bm  = blockIdx.x * 64;
    const int n   = tid & 63;
    const int mg  = tid >> 6;

    #pragma unroll
    for (int qq = 0; qq < 16; ++qq) {
        int id = qq * 256 + tid;
        int nn = id >> 6, k4 = id & 63;
        wsT[k4][nn] = *(const float4*)&w_fc[(size_t)nn * 256 + k4 * 4];
    }
    __syncthreads();

    const float bias = b_fc[n];
    const float* hrow = h2 + (size_t)(bm + mg * 16) * 256;

    float acc[16];
    #pragma unroll
    for (int mi = 0; mi < 16; ++mi) acc[mi] = 0.f;

    #pragma unroll 2
    for (int k4 = 0; k4 < 64; ++k4) {
        float4 w4 = wsT[k4][n];
        #pragma unroll
        for (int mi = 0; mi < 16; ++mi) {
            float4 h4 = *(const float4*)(hrow + (size_t)mi * 256 + k4 * 4);
            acc[mi] = fmaf(h4.x, w4.x, acc[mi]);
            acc[mi] = fmaf(h4.y, w4.y, acc[mi]);
            acc[mi] = fmaf(h4.z, w4.z, acc[mi]);
            acc[mi] = fmaf(h4.w, w4.w, acc[mi]);
        }
    }
    #pragma unroll
    for (int mi = 0; mi < 16; ++mi)
        out[(size_t)(bm + mg * 16 + mi) * 64 + n] = acc[mi] + bias;
}

extern "C" void kernel_launch(void* const* d_in, const int* in_sizes, int n_in,
                              void* d_out, int out_size, void* d_ws, size_t ws_size,
                              hipStream_t stream) {
    const float* x        = (const float*)d_in[0];
    const float* w_ih_l0  = (const float*)d_in[1];
    const float* w_hh_l0  = (const float*)d_in[2];
    const float* b_ih_l0  = (const float*)d_in[3];
    const float* b_hh_l0  = (const float*)d_in[4];
    const float* w_ih_l0r = (const float*)d_in[5];
    const float* w_hh_l0r = (const float*)d_in[6];
    const float* b_ih_l0r = (const float*)d_in[7];
    const float* b_hh_l0r = (const float*)d_in[8];
    const float* w_ih_l1  = (const float*)d_in[9];
    const float* w_hh_l1  = (const float*)d_in[10];
    const float* b_ih_l1  = (const float*)d_in[11];
    const float* b_hh_l1  = (const float*)d_in[12];
    const float* w_ih_l1r = (const float*)d_in[13];
    const float* w_hh_l1r = (const float*)d_in[14];
    const float* b_ih_l1r = (const float*)d_in[15];
    const float* b_hh_l1r = (const float*)d_in[16];
    const float* w_fc     = (const float*)d_in[17];
    const float* b_fc     = (const float*)d_in[18];

    float* ws    = (float*)d_ws;
    float* pre_f = ws;                       // 16,777,216 floats
    float* pre_b = ws + 16777216;            // 16,777,216 floats
    float* out0  = ws + 2 * 16777216;        // 8,388,608 floats
    float* out1  = out0 + 8388608;           // 8,388,608 floats

    // A hi/lo aliases (lifetimes proven R6/R7):
    short* xhi  = (short*)out0;
    short* xlo  = xhi + 2097152;
    short* a1hi = (short*)out1;
    short* a1lo = a1hi + 8388608;

    dim3 gg(256, 4);  // M/128 x 512/128

    // Layer 0
    convert_hilo<<<2048, 256, 0, stream>>>((const float4*)x, (s16x4*)xhi, (s16x4*)xlo, 524288);
    gemm_mfma2<64><<<gg, 256, 0, stream>>>(xhi, xlo, w_ih_l0,  b_ih_l0,  b_hh_l0,  pre_f);
    gemm_mfma2<64><<<gg, 256, 0, stream>>>(xhi, xlo, w_ih_l0r, b_ih_l0r, b_hh_l0r, pre_b);
    lstm_scan_v11<<<128, 512, 0, stream>>>(pre_f, pre_b, w_hh_l0, w_hh_l0r, out0);

    // Layer 1
    convert_hilo<<<2048, 256, 0, stream>>>((const float4*)out0, (s16x4*)a1hi, (s16x4*)a1lo, 2097152);
    gemm_mfma2<256><<<gg, 256, 0, stream>>>(a1hi, a1lo, w_ih_l1,  b_ih_l1,  b_hh_l1,  pre_f);
    gemm_mfma2<256><<<gg, 256, 0, stream>>>(a1hi, a1lo, w_ih_l1r, b_ih_l1r, b_hh_l1r, pre_b);
    lstm_scan_v11<<<128, 512, 0, stream>>>(pre_f, pre_b, w_hh_l1, w_hh_l1r, out1);

    // FC
    fc_v2<<<512, 256, 0, stream>>>(out1, w_fc, b_fc, (float*)d_out);
}

// Round 15
// 682.505 us; speedup vs baseline: 1.5616x; 1.1018x over previous
//
#include <hip/hip_runtime.h>

#define TT 512   // sequence length
#define BB 64    // batch
#define HH 128   // hidden
#define G4 512   // 4*H
#define PF 4     // prefetch ring depth == out-chunk size (even, divides TT)

typedef short bf16x8 __attribute__((ext_vector_type(8)));
typedef short s16x4  __attribute__((ext_vector_type(4)));
typedef float f32x4  __attribute__((ext_vector_type(4)));
typedef _Float16 f16x8v __attribute__((ext_vector_type(8)));

__device__ __forceinline__ unsigned short f2bf(float x) {
    unsigned u = __float_as_uint(x);
    u += 0x7fff + ((u >> 16) & 1);           // RNE
    return (unsigned short)(u >> 16);
}
__device__ __forceinline__ float bf2f(unsigned short h) {
    return __uint_as_float(((unsigned)h) << 16);
}

// ---------------- fp32 -> bf16 hi/lo split (memory-bound) ----------------
__global__ __launch_bounds__(256) void convert_hilo(
    const float4* __restrict__ src, s16x4* __restrict__ hi,
    s16x4* __restrict__ lo, int n4)
{
    for (int i = blockIdx.x * 256 + threadIdx.x; i < n4; i += gridDim.x * 256) {
        float4 f = src[i];
        float fa[4] = {f.x, f.y, f.z, f.w};
        s16x4 h, l;
        #pragma unroll
        for (int e = 0; e < 4; ++e) {
            unsigned short hh = f2bf(fa[e]);
            h[e] = (short)hh;
            l[e] = (short)f2bf(fa[e] - bf2f(hh));
        }
        hi[i] = h;
        lo[i] = l;
    }
}

// ---------------- MFMA pre-GEMM v2 (proven R6-R14): A pre-split, W in-kernel ----
template<int K>
__global__ __launch_bounds__(256) void gemm_mfma2(
    const short* __restrict__ Ahi, const short* __restrict__ Alo,
    const float* __restrict__ W,
    const float* __restrict__ b0, const float* __restrict__ b1,
    float* __restrict__ C)
{
    constexpr int NC  = K / 32;
    constexpr int LDA = 40;                  // shorts per staged row (32 + 8 pad)
    __shared__ short Ahi_s[128 * LDA], Alo_s[128 * LDA];
    __shared__ short Whi_s[128 * LDA], Wlo_s[128 * LDA];

    const int bm  = blockIdx.x * 128;
    const int bn  = blockIdx.y * 128;
    const int tid = threadIdx.x;
    const int wv  = tid >> 6;
    const int l   = tid & 63;
    const int jl  = l & 15;
    const int rg  = l >> 4;
    const int wr  = wv >> 1;
    const int wc  = wv & 1;

    const int sr = tid >> 1;
    const int sc = (tid & 1) * 16;

    const short* Aph = Ahi + (size_t)(bm + sr) * K + sc;
    const short* Apl = Alo + (size_t)(bm + sr) * K + sc;
    const float* Wp  = W   + (size_t)(bn + sr) * K + sc;

    f32x4 acc[4][4];
    #pragma unroll
    for (int i = 0; i < 4; ++i)
        #pragma unroll
        for (int j = 0; j < 4; ++j)
            acc[i][j] = (f32x4){0.f, 0.f, 0.f, 0.f};

    bf16x8 pah[2], pal[2];
    float4 pw[4];
    pah[0] = *(const bf16x8*)(Aph);
    pah[1] = *(const bf16x8*)(Aph + 8);
    pal[0] = *(const bf16x8*)(Apl);
    pal[1] = *(const bf16x8*)(Apl + 8);
    #pragma unroll
    for (int q = 0; q < 4; ++q) pw[q] = *(const float4*)(Wp + q * 4);

    #pragma unroll 1
    for (int c = 0; c < NC; ++c) {
        __syncthreads();
        {
            int off = sr * LDA + sc;
            *(bf16x8*)&Ahi_s[off]     = pah[0];
            *(bf16x8*)&Ahi_s[off + 8] = pah[1];
            *(bf16x8*)&Alo_s[off]     = pal[0];
            *(bf16x8*)&Alo_s[off + 8] = pal[1];
            #pragma unroll
            for (int q = 0; q < 4; ++q) {
                float fw[4] = {pw[q].x, pw[q].y, pw[q].z, pw[q].w};
                s16x4 h, lo4;
                #pragma unroll
                for (int e = 0; e < 4; ++e) {
                    unsigned short hh = f2bf(fw[e]);
                    h[e]   = (short)hh;
                    lo4[e] = (short)f2bf(fw[e] - bf2f(hh));
                }
                *(s16x4*)&Whi_s[off + q * 4] = h;
                *(s16x4*)&Wlo_s[off + q * 4] = lo4;
            }
        }
        __syncthreads();
        if (c + 1 < NC) {
            pah[0] = *(const bf16x8*)(Aph + (c + 1) * 32);
            pah[1] = *(const bf16x8*)(Aph + (c + 1) * 32 + 8);
            pal[0] = *(const bf16x8*)(Apl + (c + 1) * 32);
            pal[1] = *(const bf16x8*)(Apl + (c + 1) * 32 + 8);
            #pragma unroll
            for (int q = 0; q < 4; ++q)
                pw[q] = *(const float4*)(Wp + (c + 1) * 32 + q * 4);
        }
        bf16x8 ah[4], al[4], wh[4], wl[4];
        #pragma unroll
        for (int t = 0; t < 4; ++t) {
            int ra = (wr * 64 + t * 16 + jl) * LDA + rg * 8;
            ah[t] = *(const bf16x8*)&Ahi_s[ra];
            al[t] = *(const bf16x8*)&Alo_s[ra];
            int rw = (wc * 64 + t * 16 + jl) * LDA + rg * 8;
            wh[t] = *(const bf16x8*)&Whi_s[rw];
            wl[t] = *(const bf16x8*)&Wlo_s[rw];
        }
        #pragma unroll
        for (int tm = 0; tm < 4; ++tm)
            #pragma unroll
            for (int tn = 0; tn < 4; ++tn) {
                acc[tm][tn] = __builtin_amdgcn_mfma_f32_16x16x32_bf16(ah[tm], wh[tn], acc[tm][tn], 0, 0, 0);
                acc[tm][tn] = __builtin_amdgcn_mfma_f32_16x16x32_bf16(ah[tm], wl[tn], acc[tm][tn], 0, 0, 0);
                acc[tm][tn] = __builtin_amdgcn_mfma_f32_16x16x32_bf16(al[tm], wh[tn], acc[tm][tn], 0, 0, 0);
            }
    }

    // epilogue: C layout col=lane&15 (n), row=(lane>>4)*4+r (m)
    #pragma unroll
    for (int tn = 0; tn < 4; ++tn) {
        int n = bn + wc * 64 + tn * 16 + jl;
        float bias = b0[n] + b1[n];
        #pragma unroll
        for (int tm = 0; tm < 4; ++tm) {
            int m = bm + wr * 64 + tm * 16 + rg * 4;
            #pragma unroll
            for (int r = 0; r < 4; ++r)
                C[(size_t)(m + r) * G4 + n] = acc[tm][tn][r] + bias;
        }
    }
}

// ---------------- LSTM scan v12: per-seq MFMA recurrence ----------------
// 128 blocks = 2dir x 64batch (1 seq each), 512 thr (8 waves).
// Per step: G[512] = pre + Whh @ h as 8 waves x {4 gate-col-tiles x 4 k-chunks}
// of mfma_f32_16x16x32_f16. Wave w covers gates {cc*128 + w*16 .. +16}, cc=0..3
// (i,f,g,o of cells w*16..w*16+15). Fragment conventions HW-validated by R2's
// passing bf16 MFMA scan:
//   A[m][k]: lane holds row m=lane&15, k=(lane>>4)*8+e  (+kc*32)
//   B[n][k]: lane holds row n=lane&15 (gate), same k      (+kc*32)
//   C[m][n]: col n=lane&15, row m=(lane>>4)*4+r
// Only C row 0 (the seq's h) matters -> A rows 1-15 / C rows 1-15 are don't-
// care, so ALL lanes load the SAME wave-uniform h-chunk (no masks) and the
// junk rows are simply never read. f16 inputs (no hi/lo): same precision as
// the scalar v5-v11 scans (absmax 9.77e-4 proven).
// Tail: lanes 0-15 of each wave hold cell (w*16+l)'s i,f,g,o in acc[cc][0].
// One barrier/step; oring burst-store (v11-proven); pv-before-refill (R8-R10).
__global__ __launch_bounds__(512) void lstm_scan_v12(
    const float* __restrict__ pre_f, const float* __restrict__ pre_b,
    const float* __restrict__ whh_f, const float* __restrict__ whh_b,
    float* __restrict__ out)
{
    const int dir = blockIdx.x >> 6;
    const int b   = blockIdx.x & 63;
    const float* __restrict__ pre  = dir ? pre_b : pre_f;
    const float* __restrict__ w_hh = dir ? whh_b : whh_f;

    const int tid = threadIdx.x;
    const int w   = tid >> 6;        // wave 0..7
    const int l   = tid & 63;
    const int jl  = l & 15;
    const int rg  = l >> 4;          // 0..3

    __shared__ _Float16 h_lds[2][HH];
    __shared__ float oring[2][PF][HH];

    // B fragments: gate rows (cc*128 + w*16 + jl), k = kc*32 + rg*8 + e
    f16x8v bw[4][4];
    #pragma unroll
    for (int cc = 0; cc < 4; ++cc) {
        const float* wr_ = w_hh + (size_t)(cc * HH + w * 16 + jl) * HH + rg * 8;
        #pragma unroll
        for (int kc = 0; kc < 4; ++kc) {
            const float* p_ = wr_ + kc * 32;
            f16x8v f;
            #pragma unroll
            for (int e = 0; e < 8; ++e) f[e] = (_Float16)p_[e];
            bw[cc][kc] = f;
        }
    }

    if (tid < 2 * HH) ((_Float16*)h_lds)[tid] = (_Float16)0.f;

    // pre ring: lane pattern repeats every 16 lanes; only lanes 0-15 consumed
    const size_t base = (size_t)b * TT * G4 + w * 16 + jl;
    float pf[PF][4];
    #pragma unroll
    for (int u = 0; u < PF; ++u) {
        int tau = dir ? (TT - 1 - u) : u;
        #pragma unroll
        for (int cc = 0; cc < 4; ++cc)
            pf[u][cc] = pre[base + (size_t)tau * G4 + cc * HH];
    }

    float c = 0.f;
    const float ASIG = -1.4426950408889634f;  // -log2(e)
    const float ATAN =  2.8853900817779268f;  // 2*log2(e)

    const int s_loc = tid >> 7;      // 0..3 (PF=4)
    const int c128  = tid & 127;

    __syncthreads();

    for (int s0 = 0; s0 < TT; s0 += PF) {
        const int p = (s0 >> 2) & 1;          // oring parity for this chunk
        #pragma unroll
        for (int u = 0; u < PF; ++u) {
            const int s = s0 + u;
            const int cur = u & 1;            // parity(s) == parity(u)

            // A fragments: wave-uniform per rg-group; rows 1-15 junk (unread)
            f16x8v a[4];
            #pragma unroll
            for (int kc = 0; kc < 4; ++kc)
                a[kc] = *(const f16x8v*)&h_lds[cur][kc * 32 + rg * 8];

            // C init from pre (row 0 = real; junk rows harmless), pv BEFORE refill
            f32x4 acc[4];
            #pragma unroll
            for (int cc = 0; cc < 4; ++cc)
                acc[cc] = (f32x4){pf[u][cc], 0.f, 0.f, 0.f};

            // ring refill (clamped; full-chunk window to hide HBM latency)
            {
                int sn = s + PF;
                int taun = dir ? (TT - 1 - sn) : sn;
                taun = taun < 0 ? 0 : (taun > TT - 1 ? TT - 1 : taun);
                #pragma unroll
                for (int cc = 0; cc < 4; ++cc)
                    pf[u][cc] = pre[base + (size_t)taun * G4 + cc * HH];
            }

            // 16 MFMA: G[gates of this wave] += Whh-chunk . h-chunk
            #pragma unroll
            for (int cc = 0; cc < 4; ++cc)
                #pragma unroll
                for (int kc = 0; kc < 4; ++kc)
                    acc[cc] = __builtin_amdgcn_mfma_f32_16x16x32_f16(
                        a[kc], bw[cc][kc], acc[cc], 0, 0, 0);

            // tail: lanes 0-15 hold cell (w*16+l): i,f,g,o in acc[cc][0]
            if (l < 16) {
                float gi = acc[0][0], gf = acc[1][0], gg = acc[2][0], go = acc[3][0];
                float ei = __builtin_amdgcn_exp2f(ASIG * gi);
                float si = __builtin_amdgcn_rcpf(1.f + ei);
                float ef = __builtin_amdgcn_exp2f(ASIG * gf);
                float sf = __builtin_amdgcn_rcpf(1.f + ef);
                float eg = __builtin_amdgcn_exp2f(ATAN * gg);
                float tg = 1.f - 2.f * __builtin_amdgcn_rcpf(1.f + eg);
                float eo = __builtin_amdgcn_exp2f(ASIG * go);
                float so = __builtin_amdgcn_rcpf(1.f + eo);
                c = fmaf(sf, c, si * tg);
                float e2 = __builtin_amdgcn_exp2f(ATAN * c);
                float h  = so * (1.f - 2.f * __builtin_amdgcn_rcpf(1.f + e2));
                int j = w * 16 + l;
                h_lds[cur ^ 1][j] = (_Float16)h;
                oring[p][u][j] = h;
            }
            __syncthreads();
        }

        // coalesced burst-write of the finished chunk (opposite parity next
        // chunk; >=2 barriers separate reuse of this half -> race-free)
        {
            int sb = s0 + s_loc;
            int tau = dir ? (TT - 1 - sb) : sb;
            out[((size_t)b * TT + tau) * (2 * HH) + dir * HH + c128] =
                oring[p][s_loc][c128];
        }
    }
}

// ---------------- FC v2 (proven R7) ----------------
__global__ __launch_bounds__(256) void fc_v2(
    const float* __restrict__ h2, const float* __restrict__ w_fc,
    const float* __restrict__ b_fc, float* __restrict__ out)
{
    __shared__ float4 wsT[64][64];          // [k4][n]
    const int tid = threadIdx.x;
    const int bm  = blockIdx.x * 64;
    const int n   = tid & 63;
    const int mg  = tid >> 6;

    #pragma unroll
    for (int qq = 0; qq < 16; ++qq) {
        int id = qq * 256 + tid;
        int nn = id >> 6, k4 = id & 63;
        wsT[k4][nn] = *(const float4*)&w_fc[(size_t)nn * 256 + k4 * 4];
    }
    __syncthreads();

    const float bias = b_fc[n];
    const float* hrow = h2 + (size_t)(bm + mg * 16) * 256;

    float acc[16];
    #pragma unroll
    for (int mi = 0; mi < 16; ++mi) acc[mi] = 0.f;

    #pragma unroll 2
    for (int k4 = 0; k4 < 64; ++k4) {
        float4 w4 = wsT[k4][n];
        #pragma unroll
        for (int mi = 0; mi < 16; ++mi) {
            float4 h4 = *(const float4*)(hrow + (size_t)mi * 256 + k4 * 4);
            acc[mi] = fmaf(h4.x, w4.x, acc[mi]);
            acc[mi] = fmaf(h4.y, w4.y, acc[mi]);
            acc[mi] = fmaf(h4.z, w4.z, acc[mi]);
            acc[mi] = fmaf(h4.w, w4.w, acc[mi]);
        }
    }
    #pragma unroll
    for (int mi = 0; mi < 16; ++mi)
        out[(size_t)(bm + mg * 16 + mi) * 64 + n] = acc[mi] + bias;
}

extern "C" void kernel_launch(void* const* d_in, const int* in_sizes, int n_in,
                              void* d_out, int out_size, void* d_ws, size_t ws_size,
                              hipStream_t stream) {
    const float* x        = (const float*)d_in[0];
    const float* w_ih_l0  = (const float*)d_in[1];
    const float* w_hh_l0  = (const float*)d_in[2];
    const float* b_ih_l0  = (const float*)d_in[3];
    const float* b_hh_l0  = (const float*)d_in[4];
    const float* w_ih_l0r = (const float*)d_in[5];
    const float* w_hh_l0r = (const float*)d_in[6];
    const float* b_ih_l0r = (const float*)d_in[7];
    const float* b_hh_l0r = (const float*)d_in[8];
    const float* w_ih_l1  = (const float*)d_in[9];
    const float* w_hh_l1  = (const float*)d_in[10];
    const float* b_ih_l1  = (const float*)d_in[11];
    const float* b_hh_l1  = (const float*)d_in[12];
    const float* w_ih_l1r = (const float*)d_in[13];
    const float* w_hh_l1r = (const float*)d_in[14];
    const float* b_ih_l1r = (const float*)d_in[15];
    const float* b_hh_l1r = (const float*)d_in[16];
    const float* w_fc     = (const float*)d_in[17];
    const float* b_fc     = (const float*)d_in[18];

    float* ws    = (float*)d_ws;
    float* pre_f = ws;                       // 16,777,216 floats
    float* pre_b = ws + 16777216;            // 16,777,216 floats
    float* out0  = ws + 2 * 16777216;        // 8,388,608 floats
    float* out1  = out0 + 8388608;           // 8,388,608 floats

    // A hi/lo aliases (lifetimes proven R6/R7):
    short* xhi  = (short*)out0;
    short* xlo  = xhi + 2097152;
    short* a1hi = (short*)out1;
    short* a1lo = a1hi + 8388608;

    dim3 gg(256, 4);  // M/128 x 512/128

    // Layer 0
    convert_hilo<<<2048, 256, 0, stream>>>((const float4*)x, (s16x4*)xhi, (s16x4*)xlo, 524288);
    gemm_mfma2<64><<<gg, 256, 0, stream>>>(xhi, xlo, w_ih_l0,  b_ih_l0,  b_hh_l0,  pre_f);
    gemm_mfma2<64><<<gg, 256, 0, stream>>>(xhi, xlo, w_ih_l0r, b_ih_l0r, b_hh_l0r, pre_b);
    lstm_scan_v12<<<128, 512, 0, stream>>>(pre_f, pre_b, w_hh_l0, w_hh_l0r, out0);

    // Layer 1
    convert_hilo<<<2048, 256, 0, stream>>>((const float4*)out0, (s16x4*)a1hi, (s16x4*)a1lo, 2097152);
    gemm_mfma2<256><<<gg, 256, 0, stream>>>(a1hi, a1lo, w_ih_l1,  b_ih_l1,  b_hh_l1,  pre_f);
    gemm_mfma2<256><<<gg, 256, 0, stream>>>(a1hi, a1lo, w_ih_l1r, b_ih_l1r, b_hh_l1r, pre_b);
    lstm_scan_v12<<<128, 512, 0, stream>>>(pre_f, pre_b, w_hh_l1, w_hh_l1r, out1);

    // FC
    fc_v2<<<512, 256, 0, stream>>>(out1, w_fc, b_fc, (float*)d_out);
}